// Round 4
// baseline (2904.503 us; speedup 1.0000x reference)
//
#include <hip/hip_runtime.h>
#include <hip/hip_bf16.h>
#include <math.h>
#include <cstdio>

// TMSA block, dual-dtype self-detecting pipeline.
// A detector kernel inspects x's raw halfwords and writes mode flag to ws:
//   1 = I/O tensors are bf16, 0 = I/O tensors are fp32.
// Both template chains are launched; each kernel early-outs unless flag==MODE.
// Intermediates are always bf16 in ws:
//   [0,          35389440)  xw   bf16 98304x180   (LN1 out; later LN2 out)
//   [35389440,  106168320)  attn bf16 98304x360   (attn out; later MLP hidden)
//   [106168320, 212336640)  qkv  bf16 3 x 768x6x128x30
//   [212336640, +4)         mode flag (int)
// res (x + proj) lives in d_out, updated in-place by fc2.

typedef __hip_bfloat16 bf16;

#define CC 180
#define SZQ 17694720            // 768*6*128*30
#define SCALE_F 0.18257418583505536f   // 30^-0.5
#define FLAG_OFF 212336640

__device__ __forceinline__ float b2f(bf16 v){ return __bfloat162float(v); }
__device__ __forceinline__ bf16  f2b(float v){ return __float2bfloat16(v); }

__device__ __forceinline__ float ld(const bf16* p, size_t i){ return __bfloat162float(p[i]); }
__device__ __forceinline__ float ld(const float* p, size_t i){ return p[i]; }
__device__ __forceinline__ void  st(bf16* p, size_t i, float v){ p[i] = __float2bfloat16(v); }
__device__ __forceinline__ void  st(float* p, size_t i, float v){ p[i] = v; }

// ---------------------------------------------------------------- dtype probe
// Sample even halfwords of x. bf16 mode: they are bf16(N(0,1)) -> exp in [0x5A,0x84]
// essentially always. fp32 mode: they are low mantissa bits -> ~17% land in range.
__global__ void k_detect(const unsigned short* __restrict__ xraw, int* __restrict__ flag)
{
    int lane = threadIdx.x;             // 64 threads
    unsigned short v = xraw[2 * lane];
    int e = (v >> 7) & 0xFF;
    bool sane = ((v & 0x7FFF) == 0) || (e >= 0x5A && e <= 0x84);
    unsigned long long m = __ballot(sane);
    if (lane == 0) flag[0] = (__popcll(m) >= 40) ? 1 : 0;
}

// ---------------------------------------------------------------- LayerNorm
template<typename T, int MODE, bool ROLL>
__global__ __launch_bounds__(256) void k_ln(const T* __restrict__ x,
                                            const T* __restrict__ g,
                                            const T* __restrict__ b,
                                            bf16* __restrict__ outp,
                                            const int* __restrict__ flag)
{
    if (flag[0] != MODE) return;
    int row  = blockIdx.x * 4 + (threadIdx.x >> 6);
    int lane = threadIdx.x & 63;
    const T* src;
    if (ROLL) {
        int win = row >> 7, tok = row & 127;
        int wd = win >> 8, wh = (win >> 4) & 15, ww = win & 15;
        int td = tok >> 6, th = (tok >> 3) & 7, tw = tok & 7;
        int d = wd * 2 + td + 1; if (d >= 6) d -= 6;
        int h = (wh * 8 + th + 4) & 127;
        int w = (ww * 8 + tw + 4) & 127;
        src = x + ((size_t)((d * 128 + h) * 128 + w)) * CC;
    } else {
        src = x + (size_t)row * CC;
    }
    float v0 = ld(src, lane);
    float v1 = ld(src, lane + 64);
    float v2 = (lane < 52) ? ld(src, lane + 128) : 0.f;
    float s  = v0 + v1 + v2;
    float ss = v0*v0 + v1*v1 + v2*v2;
    #pragma unroll
    for (int o = 32; o > 0; o >>= 1) { s += __shfl_xor(s, o, 64); ss += __shfl_xor(ss, o, 64); }
    float mean = s * (1.f/180.f);
    float var  = ss * (1.f/180.f) - mean*mean;
    float rstd = rsqrtf(var + 1e-5f);
    bf16* dst = outp + (size_t)row * CC;
    dst[lane]    = f2b((v0-mean)*rstd*ld(g,lane)    + ld(b,lane));
    dst[lane+64] = f2b((v1-mean)*rstd*ld(g,lane+64) + ld(b,lane+64));
    if (lane < 52)
        dst[lane+128] = f2b((v2-mean)*rstd*ld(g,lane+128) + ld(b,lane+128));
}

// ---------------------------------------------------------------- GEMM core
// bf16 A (ws) x T B (weights), fp32 accum. 64x64 tile, 256 thr, 4x4 micro-tile.
template<typename T, int K, int NW, bool DUAL, bool ADD_PB>
__device__ __forceinline__ void gemm_tile(const bf16* __restrict__ A,
                                          const T* __restrict__ pb,
                                          const T* __restrict__ B1,
                                          const T* __restrict__ B2,
                                          float (&acc1)[4][4], float (&acc2)[4][4])
{
    __shared__ float As[16][65];
    __shared__ float Bs1[16][64];
    __shared__ float Bs2[DUAL ? 16 : 1][64];
    const int m0 = blockIdx.x * 64, n0 = blockIdx.y * 64;
    const int tid = threadIdx.x;
    const int r0 = (tid >> 4) << 2, c0 = (tid & 15) << 2;

    for (int k0 = 0; k0 < K; k0 += 16) {
        #pragma unroll
        for (int i = 0; i < 4; i++) {
            int idx = tid + i * 256;
            int m = idx >> 4, k = idx & 15;
            float v = 0.f;
            if (k0 + k < K) {
                v = b2f(A[(size_t)(m0 + m) * K + (k0 + k)]);
                if (ADD_PB) v += ld(pb, ((m0 + m) & 63) * CC + (k0 + k));
            }
            As[k][m] = v;
        }
        #pragma unroll
        for (int i = 0; i < 4; i++) {
            int idx = tid + i * 256;
            int k = idx >> 6, n = idx & 63;
            bool ok = (k0 + k < K) && (n0 + n < NW);
            Bs1[k][n] = ok ? ld(B1, (size_t)(k0 + k) * NW + (n0 + n)) : 0.f;
            if (DUAL)
                Bs2[k][n] = ok ? ld(B2, (size_t)(k0 + k) * NW + (n0 + n)) : 0.f;
        }
        __syncthreads();
        #pragma unroll
        for (int k = 0; k < 16; k++) {
            float a[4];
            #pragma unroll
            for (int i = 0; i < 4; i++) a[i] = As[k][r0 + i];
            #pragma unroll
            for (int j = 0; j < 4; j++) {
                float bb = Bs1[k][c0 + j];
                #pragma unroll
                for (int i = 0; i < 4; i++) acc1[i][j] += a[i] * bb;
            }
            if (DUAL) {
                #pragma unroll
                for (int j = 0; j < 4; j++) {
                    float bb = Bs2[k][c0 + j];
                    #pragma unroll
                    for (int i = 0; i < 4; i++) acc2[i][j] += a[i] * bb;
                }
            }
        }
        __syncthreads();
    }
}

// QKV GEMM (K=180, N=540): +bias, scatter to qkv [three][win*6+nh][tok][hd] bf16.
template<typename T, int MODE, bool ADD_PB>
__global__ __launch_bounds__(256) void k_qkv(const bf16* __restrict__ A,
                                             const T* __restrict__ pb,
                                             const T* __restrict__ Bw,
                                             const T* __restrict__ bias,
                                             bf16* __restrict__ outq,
                                             const int* __restrict__ flag)
{
    if (flag[0] != MODE) return;
    float a1[4][4] = {}, a2[4][4] = {};
    gemm_tile<T, 180, 540, false, ADD_PB>(A, pb, Bw, nullptr, a1, a2);
    int m0 = blockIdx.x * 64, n0 = blockIdx.y * 64;
    int r0 = (threadIdx.x >> 4) << 2, c0 = (threadIdx.x & 15) << 2;
    #pragma unroll
    for (int i = 0; i < 4; i++) {
        int row = m0 + r0 + i;
        int win = row >> 7, tok = row & 127;
        #pragma unroll
        for (int j = 0; j < 4; j++) {
            int col = n0 + c0 + j;
            if (col < 540) {
                float v = a1[i][j] + ld(bias, col);
                int three = col / 180, rem = col - three * 180;
                int nh = rem / 30, hd = rem - nh * 30;
                outq[(size_t)three * SZQ + ((size_t)(win * 6 + nh) * 128 + tok) * 30 + hd] = f2b(v);
            }
        }
    }
}

// ---------------------------------------------------------------- attention
template<typename T, int MODE>
__global__ __launch_bounds__(128) void k_attn_self(const bf16* __restrict__ qkv,
                                                   const T* __restrict__ rpb,
                                                   const int*  __restrict__ rpi,
                                                   const T* __restrict__ mask,
                                                   bf16* __restrict__ attn_out,
                                                   const int* __restrict__ flag)
{
    if (flag[0] != MODE) return;
    int wh = blockIdx.x;             // win*6 + nh
    int win = wh / 6, nh = wh - win * 6;
    __shared__ float kS[128 * 30];
    __shared__ float vS[128 * 30];
    const bf16* qb = qkv + (size_t)wh * 3840;
    const bf16* kb = qb + SZQ;
    const bf16* vb = qb + 2 * (size_t)SZQ;
    int t = threadIdx.x;
    for (int i = t; i < 3840; i += 128) { kS[i] = b2f(kb[i]); vS[i] = b2f(vb[i]); }
    float q[30];
    #pragma unroll
    for (int i = 0; i < 30; i++) q[i] = b2f(qb[t * 30 + i]) * SCALE_F;
    __syncthreads();

    const int* rpirow = rpi + t * 128;
    const T*   mrow   = mask + ((size_t)win * 128 + t) * 128;
    float mx = -1e30f, l = 0.f, o[30];
    #pragma unroll
    for (int i = 0; i < 30; i++) o[i] = 0.f;
    for (int m = 0; m < 128; m++) {
        float s = 0.f;
        #pragma unroll
        for (int i = 0; i < 30; i++) s += q[i] * kS[m * 30 + i];
        s += ld(rpb, (size_t)rpirow[m] * 6 + nh) + ld(mrow, m);
        float mn   = fmaxf(mx, s);
        float corr = __expf(mx - mn);
        float p    = __expf(s - mn);
        l = l * corr + p;
        #pragma unroll
        for (int i = 0; i < 30; i++) o[i] = o[i] * corr + p * vS[m * 30 + i];
        mx = mn;
    }
    float inv = 1.f / l;
    bf16* dst = attn_out + ((size_t)win * 128 + t) * 360 + 180 + nh * 30;
    #pragma unroll
    for (int i = 0; i < 30; i++) dst[i] = f2b(o[i] * inv);
}

template<typename T, int MODE>
__global__ __launch_bounds__(128) void k_attn_mut(const bf16* __restrict__ qkv,
                                                  const T* __restrict__ mask,
                                                  bf16* __restrict__ attn_out,
                                                  const int* __restrict__ flag)
{
    if (flag[0] != MODE) return;
    int wh = blockIdx.x;
    int win = wh / 6, nh = wh - win * 6;
    __shared__ float kS[128 * 30];
    __shared__ float vS[128 * 30];
    const bf16* qb = qkv + (size_t)wh * 3840;
    const bf16* kb = qb + SZQ;
    const bf16* vb = qb + 2 * (size_t)SZQ;
    int t = threadIdx.x;
    for (int i = t; i < 3840; i += 128) { kS[i] = b2f(kb[i]); vS[i] = b2f(vb[i]); }
    int qrow = (t < 64) ? 64 + t : t - 64;   // x1=attn(q2,k1,v1) rows 0..63; x2 rows 64..127
    int kv0  = (t < 64) ? 0 : 64;
    float q[30];
    #pragma unroll
    for (int i = 0; i < 30; i++) q[i] = b2f(qb[qrow * 30 + i]) * SCALE_F;
    __syncthreads();

    const T* mrow = mask + ((size_t)win * 128 + (t & 63)) * 128;  // m2 row, cols 0..63
    float mx = -1e30f, l = 0.f, o[30];
    #pragma unroll
    for (int i = 0; i < 30; i++) o[i] = 0.f;
    for (int m = 0; m < 64; m++) {
        int km = kv0 + m;
        float s = 0.f;
        #pragma unroll
        for (int i = 0; i < 30; i++) s += q[i] * kS[km * 30 + i];
        s += ld(mrow, m);
        float mn   = fmaxf(mx, s);
        float corr = __expf(mx - mn);
        float p    = __expf(s - mn);
        l = l * corr + p;
        #pragma unroll
        for (int i = 0; i < 30; i++) o[i] = o[i] * corr + p * vS[km * 30 + i];
        mx = mn;
    }
    float inv = 1.f / l;
    bf16* dst = attn_out + ((size_t)win * 128 + t) * 360 + nh * 30;
    #pragma unroll
    for (int i = 0; i < 30; i++) dst[i] = f2b(o[i] * inv);
}

// proj (K=360,N=180) + window-reverse + roll + residual(+x) -> d_out (T)
template<typename T, int MODE>
__global__ __launch_bounds__(256) void k_proj(const bf16* __restrict__ A,
                                              const T* __restrict__ Bw,
                                              const T* __restrict__ bias,
                                              const T* __restrict__ xin,
                                              T* __restrict__ res,
                                              const int* __restrict__ flag)
{
    if (flag[0] != MODE) return;
    float a1[4][4] = {}, a2[4][4] = {};
    gemm_tile<T, 360, 180, false, false>(A, nullptr, Bw, nullptr, a1, a2);
    int m0 = blockIdx.x * 64, n0 = blockIdx.y * 64;
    int r0 = (threadIdx.x >> 4) << 2, c0 = (threadIdx.x & 15) << 2;
    #pragma unroll
    for (int i = 0; i < 4; i++) {
        int row = m0 + r0 + i;
        int win = row >> 7, tok = row & 127;
        int wd = win >> 8, wh = (win >> 4) & 15, ww = win & 15;
        int td = tok >> 6, th = (tok >> 3) & 7, tw = tok & 7;
        int d = wd * 2 + td + 1; if (d >= 6) d -= 6;
        int h = (wh * 8 + th + 4) & 127;
        int w = (ww * 8 + tw + 4) & 127;
        size_t base = ((size_t)((d * 128 + h) * 128 + w)) * CC;
        #pragma unroll
        for (int j = 0; j < 4; j++) {
            int col = n0 + c0 + j;
            if (col < 180)
                st(res, base + col, ld(xin, base + col) + a1[i][j] + ld(bias, col));
        }
    }
}

// fc1: h @ {w11,w12} -> gelu(x1)*x2 -> hid (bf16)
template<typename T, int MODE>
__global__ __launch_bounds__(256) void k_fc1(const bf16* __restrict__ A,
                                             const T* __restrict__ B1,
                                             const T* __restrict__ bb1,
                                             const T* __restrict__ B2,
                                             const T* __restrict__ bb2,
                                             bf16* __restrict__ hid,
                                             const int* __restrict__ flag)
{
    if (flag[0] != MODE) return;
    float a1[4][4] = {}, a2[4][4] = {};
    gemm_tile<T, 180, 360, true, false>(A, nullptr, B1, B2, a1, a2);
    int m0 = blockIdx.x * 64, n0 = blockIdx.y * 64;
    int r0 = (threadIdx.x >> 4) << 2, c0 = (threadIdx.x & 15) << 2;
    #pragma unroll
    for (int i = 0; i < 4; i++) {
        int row = m0 + r0 + i;
        #pragma unroll
        for (int j = 0; j < 4; j++) {
            int col = n0 + c0 + j;
            if (col < 360) {
                float gate = a1[i][j] + ld(bb1, col);
                float gl = 0.5f * gate * (1.f + erff(gate * 0.70710678118654752f));
                hid[(size_t)row * 360 + col] = f2b(gl * (a2[i][j] + ld(bb2, col)));
            }
        }
    }
}

// fc2: hid @ w2 + b + res(d_out) -> d_out, in-place per element
template<typename T, int MODE>
__global__ __launch_bounds__(256) void k_fc2(const bf16* __restrict__ A,
                                             const T* __restrict__ Bw,
                                             const T* __restrict__ bias,
                                             T* __restrict__ out,
                                             const int* __restrict__ flag)
{
    if (flag[0] != MODE) return;
    float a1[4][4] = {}, a2[4][4] = {};
    gemm_tile<T, 360, 180, false, false>(A, nullptr, Bw, nullptr, a1, a2);
    int m0 = blockIdx.x * 64, n0 = blockIdx.y * 64;
    int r0 = (threadIdx.x >> 4) << 2, c0 = (threadIdx.x & 15) << 2;
    #pragma unroll
    for (int i = 0; i < 4; i++) {
        int row = m0 + r0 + i;
        #pragma unroll
        for (int j = 0; j < 4; j++) {
            int col = n0 + c0 + j;
            if (col < 180) {
                size_t idx = (size_t)row * CC + col;
                st(out, idx, ld((const T*)out, idx) + a1[i][j] + ld(bias, col));
            }
        }
    }
}

// ---------------------------------------------------------------- chain
template<typename T, int MODE>
static void run_chain(void* const* d_in, void* d_out, void* d_ws,
                      const int* flag, hipStream_t stream)
{
    const T* x     = (const T*)d_in[0];
    const T* mask  = (const T*)d_in[1];
    const T* g1    = (const T*)d_in[2];
    const T* b1    = (const T*)d_in[3];
    const T* g2    = (const T*)d_in[4];
    const T* b2    = (const T*)d_in[5];
    const T* wqs   = (const T*)d_in[6];
    const T* bqs   = (const T*)d_in[7];
    const T* wqm   = (const T*)d_in[8];
    const T* bqm   = (const T*)d_in[9];
    const T* rpb   = (const T*)d_in[10];
    const T* posb  = (const T*)d_in[11];
    const T* wproj = (const T*)d_in[12];
    const T* bproj = (const T*)d_in[13];
    const T* w11   = (const T*)d_in[14];
    const T* bf11  = (const T*)d_in[15];
    const T* w12   = (const T*)d_in[16];
    const T* bf12  = (const T*)d_in[17];
    const T* w2    = (const T*)d_in[18];
    const T* bf2   = (const T*)d_in[19];
    const int* rpi = (const int*)d_in[20];
    T* out = (T*)d_out;

    bf16* xw   = (bf16*)d_ws;                                   // 98304x180
    bf16* attn = (bf16*)((char*)d_ws + (size_t)35389440);       // 98304x360
    bf16* qkv  = (bf16*)((char*)d_ws + (size_t)106168320);      // 3 x SZQ

    k_ln<T,MODE,true><<<dim3(24576), 256, 0, stream>>>(x, g1, b1, xw, flag);
    k_qkv<T,MODE,false><<<dim3(1536, 9), 256, 0, stream>>>(xw, (const T*)nullptr, wqs, bqs, qkv, flag);
    k_attn_self<T,MODE><<<dim3(4608), 128, 0, stream>>>(qkv, rpb, rpi, mask, attn, flag);
    k_qkv<T,MODE,true><<<dim3(1536, 9), 256, 0, stream>>>(xw, posb, wqm, bqm, qkv, flag);
    k_attn_mut<T,MODE><<<dim3(4608), 128, 0, stream>>>(qkv, mask, attn, flag);
    k_proj<T,MODE><<<dim3(1536, 3), 256, 0, stream>>>(attn, wproj, bproj, x, out, flag);
    k_ln<T,MODE,false><<<dim3(24576), 256, 0, stream>>>(out, g2, b2, xw, flag);
    k_fc1<T,MODE><<<dim3(1536, 6), 256, 0, stream>>>(xw, w11, bf11, w12, bf12, attn, flag);
    k_fc2<T,MODE><<<dim3(1536, 3), 256, 0, stream>>>(attn, w2, bf2, out, flag);
}

// ---------------------------------------------------------------- launch
extern "C" void kernel_launch(void* const* d_in, const int* in_sizes, int n_in,
                              void* d_out, int out_size, void* d_ws, size_t ws_size,
                              hipStream_t stream)
{
    const size_t need = FLAG_OFF + 256;
    if (ws_size < need) { fprintf(stderr, "[tmsa] ws too small: %zu < %zu\n", ws_size, need); return; }

    int* flag = (int*)((char*)d_ws + FLAG_OFF);
    k_detect<<<1, 64, 0, stream>>>((const unsigned short*)d_in[0], flag);

    run_chain<bf16, 1>(d_in, d_out, d_ws, flag, stream);
    run_chain<float, 0>(d_in, d_out, d_ws, flag, stream);
}

// Round 6
// 1358.379 us; speedup vs baseline: 2.1382x; 2.1382x over previous
//
#include <hip/hip_runtime.h>
#include <hip/hip_bf16.h>
#include <math.h>
#include <cstdio>

// TMSA block, fp32 I/O (proven R4), bf16 MFMA internals.
// ws layout (bytes), total ~260 MB of 270 MB:
//   [0,          37748736)   xw   bf16 [98304][192]  (LN1 out, k-padded; later LN2 out)
//   [37748736,  75497472)    xwm  bf16 [98304][192]  (xw + pos_bias, for mutual qkv)
//   [75497472,  146276352)   attn bf16 [98304][360]  (attn out; later MLP hidden)
//   [146276352, 259522560)   qkv  bf16 [3][4608][128][32] (hd padded 30->32, q pre-scaled)
//   [259522560, 259915776)   biasr fp32 [6][128][128] (rpb gathered)
// res (x + proj) lives in d_out (fp32), updated in-place by fc2.

typedef __hip_bfloat16 bf16;
typedef __attribute__((ext_vector_type(8))) short short8;
typedef __attribute__((ext_vector_type(4))) float f32x4;

#define SCALE_F 0.18257418583505536f   // 30^-0.5
#define SZPE 18874368u                 // elems per qkv tensor: 4608*128*32

__device__ __forceinline__ bf16  f2b(float v){ return __float2bfloat16(v); }
__device__ __forceinline__ float b2f(bf16 v){ return __bfloat162float(v); }
__device__ __forceinline__ f32x4 mfma16(short8 a, short8 b, f32x4 c){
    return __builtin_amdgcn_mfma_f32_16x16x32_bf16(a, b, c, 0, 0, 0);
}

// ---------------------------------------------------------------- rpb gather
// biasr[nh][r][c] = rpb[rpi[r*128+c]*6 + nh]
__global__ __launch_bounds__(256) void k_rpbg(const float* __restrict__ rpb,
                                              const int* __restrict__ rpi,
                                              float* __restrict__ biasr)
{
    int n = blockIdx.x * 256 + threadIdx.x;       // < 98304
    int nh = n >> 14, rc = n & 16383;
    biasr[n] = rpb[rpi[rc] * 6 + nh];
}

// ---------------------------------------------------------------- qkv pad zero
// zero hd columns 30,31 of every row in the qkv buffer (once per launch)
__global__ __launch_bounds__(256) void k_padzero(bf16* __restrict__ qkv)
{
    int id = blockIdx.x * 256 + threadIdx.x;      // < 1769472 = 3*4608*128
    *(unsigned int*)((char*)qkv + (size_t)id * 64 + 60) = 0u;
}

// ---------------------------------------------------------------- LayerNorm
// One wave per 180-ch token row. ROLL_PB: shifted-window gather + write xwm = xw + pos_bias.
template<bool ROLL_PB>
__global__ __launch_bounds__(256) void k_ln(const float* __restrict__ x,
                                            const float* __restrict__ g,
                                            const float* __restrict__ b,
                                            const float* __restrict__ pb,
                                            bf16* __restrict__ xw,
                                            bf16* __restrict__ xwm)
{
    int row  = blockIdx.x * 4 + (threadIdx.x >> 6);
    int lane = threadIdx.x & 63;
    const float* src;
    if (ROLL_PB) {
        int win = row >> 7, tok = row & 127;
        int wd = win >> 8, wh = (win >> 4) & 15, ww = win & 15;
        int td = tok >> 6, th = (tok >> 3) & 7, tw = tok & 7;
        int d = wd * 2 + td + 1; if (d >= 6) d -= 6;
        int h = (wh * 8 + th + 4) & 127;
        int w = (ww * 8 + tw + 4) & 127;
        src = x + ((size_t)((d * 128 + h) * 128 + w)) * 180;
    } else {
        src = x + (size_t)row * 180;
    }
    float v0 = src[lane];
    float v1 = src[lane + 64];
    float v2 = (lane < 52) ? src[lane + 128] : 0.f;
    float s  = v0 + v1 + v2;
    float ss = v0*v0 + v1*v1 + v2*v2;
    #pragma unroll
    for (int o = 32; o > 0; o >>= 1) { s += __shfl_xor(s, o, 64); ss += __shfl_xor(ss, o, 64); }
    float mean = s * (1.f/180.f);
    float var  = ss * (1.f/180.f) - mean*mean;
    float rstd = rsqrtf(var + 1e-5f);

    bf16* dst = xw + (size_t)row * 192;
    float y0 = (v0-mean)*rstd*g[lane]     + b[lane];
    float y1 = (v1-mean)*rstd*g[lane+64]  + b[lane+64];
    float y2 = (lane < 52) ? ((v2-mean)*rstd*g[lane+128] + b[lane+128]) : 0.f;
    dst[lane]      = f2b(y0);
    dst[lane+64]   = f2b(y1);
    if (lane < 52) dst[lane+128] = f2b(y2);
    if (lane < 12) dst[180+lane] = f2b(0.f);
    if (ROLL_PB) {
        const float* pbr = pb + (size_t)(row & 63) * 180;
        bf16* dm = xwm + (size_t)row * 192;
        dm[lane]      = f2b(y0 + pbr[lane]);
        dm[lane+64]   = f2b(y1 + pbr[lane+64]);
        if (lane < 52) dm[lane+128] = f2b(y2 + pbr[lane+128]);
        if (lane < 12) dm[180+lane] = f2b(0.f);
    }
}

// ---------------------------------------------------------------- MFMA GEMM core
// C[M x NW] = A[M x K](bf16, row stride AS) @ B[K x NW](fp32 weights).
// Block: 256 thr = 4 waves; tile 128(M) x 64(N); wave w owns rows w*32..w*32+31.
template<int K, int NW, int AS, bool DUAL>
__device__ __forceinline__ void mm_core(const bf16* __restrict__ A,
                                        const float* __restrict__ B1,
                                        const float* __restrict__ B2,
                                        f32x4 (&acc1)[2][4], f32x4 (&acc2)[2][4])
{
    __shared__ __align__(16) bf16 As[128 * 72];
    __shared__ __align__(16) bf16 Bs1[64 * 72];
    __shared__ __align__(16) bf16 Bs2[DUAL ? 64 * 72 : 8];
    const int m0 = blockIdx.x * 128, n0 = blockIdx.y * 64;
    const int tid = threadIdx.x;
    const int w = tid >> 6, l = tid & 63, q = l >> 4, c = l & 15;
    constexpr int KSTEPS = (K + 63) / 64;

    for (int ks = 0; ks < KSTEPS; ks++) {
        // stage A tile 128x64 (uint4 = 8 bf16 per load): 1024 loads / 256 thr
        #pragma unroll
        for (int gidx = 0; gidx < 4; gidx++) {
            int gi = gidx * 256 + tid;          // < 1024
            int m = gi >> 3, kk = (gi & 7) * 8;
            int gk = ks * 64 + kk;
            uint4 v;
            if (AS >= KSTEPS * 64 || gk + 8 <= K)
                v = *(const uint4*)(A + (size_t)(m0 + m) * AS + gk);
            else
                v = make_uint4(0u, 0u, 0u, 0u);
            *(uint4*)&As[m * 72 + kk] = v;
        }
        // stage B tile 64x64 transposed (fp32 -> bf16)
        #pragma unroll
        for (int e = 0; e < 16; e++) {
            int gi = e * 256 + tid;             // < 4096
            int n = gi & 63, k = gi >> 6;
            int gk = ks * 64 + k;
            bool ok = (gk < K) && (n0 + n < NW);
            Bs1[n * 72 + k] = f2b(ok ? B1[(size_t)gk * NW + (n0 + n)] : 0.f);
            if (DUAL)
                Bs2[n * 72 + k] = f2b(ok ? B2[(size_t)gk * NW + (n0 + n)] : 0.f);
        }
        __syncthreads();
        #pragma unroll
        for (int k32 = 0; k32 < 2; k32++) {
            short8 a[2];
            #pragma unroll
            for (int mt = 0; mt < 2; mt++)
                a[mt] = *(const short8*)&As[(w * 32 + mt * 16 + c) * 72 + k32 * 32 + q * 8];
            #pragma unroll
            for (int nt = 0; nt < 4; nt++) {
                short8 b1 = *(const short8*)&Bs1[(nt * 16 + c) * 72 + k32 * 32 + q * 8];
                #pragma unroll
                for (int mt = 0; mt < 2; mt++) acc1[mt][nt] = mfma16(a[mt], b1, acc1[mt][nt]);
                if (DUAL) {
                    short8 b2 = *(const short8*)&Bs2[(nt * 16 + c) * 72 + k32 * 32 + q * 8];
                    #pragma unroll
                    for (int mt = 0; mt < 2; mt++) acc2[mt][nt] = mfma16(a[mt], b2, acc2[mt][nt]);
                }
            }
        }
        __syncthreads();
    }
}

// qkv GEMM: K=180, N=540; scatter +bias (q *= SCALE) to qkv buffer (hd pad 32).
__global__ __launch_bounds__(256) void k_qkv(const bf16* __restrict__ A,
                                             const float* __restrict__ Bw,
                                             const float* __restrict__ bias,
                                             bf16* __restrict__ outq)
{
    f32x4 a1[2][4] = {}, a2[2][4] = {};
    mm_core<180, 540, 192, false>(A, Bw, nullptr, a1, a2);
    int m0 = blockIdx.x * 128, n0 = blockIdx.y * 64;
    int w = threadIdx.x >> 6, l = threadIdx.x & 63, q = l >> 4, c = l & 15;
    #pragma unroll
    for (int mt = 0; mt < 2; mt++)
      #pragma unroll
      for (int nt = 0; nt < 4; nt++)
        #pragma unroll
        for (int r = 0; r < 4; r++) {
            int row = m0 + w * 32 + mt * 16 + q * 4 + r;
            int col = n0 + nt * 16 + c;
            if (col < 540) {
                float v = a1[mt][nt][r] + bias[col];
                int three = col / 180, rem = col - three * 180;
                int nh = rem / 30, hd = rem - nh * 30;
                if (three == 0) v *= SCALE_F;
                int win = row >> 7, tok = row & 127;
                outq[(size_t)three * SZPE + ((size_t)(win * 6 + nh) * 128 + tok) * 32 + hd] = f2b(v);
            }
        }
}

// proj GEMM: K=360, N=180; window-reverse + roll + residual(+x) -> d_out fp32.
__global__ __launch_bounds__(256) void k_proj(const bf16* __restrict__ A,
                                              const float* __restrict__ Bw,
                                              const float* __restrict__ bias,
                                              const float* __restrict__ xin,
                                              float* __restrict__ res)
{
    f32x4 a1[2][4] = {}, a2[2][4] = {};
    mm_core<360, 180, 360, false>(A, Bw, nullptr, a1, a2);
    int m0 = blockIdx.x * 128, n0 = blockIdx.y * 64;
    int w = threadIdx.x >> 6, l = threadIdx.x & 63, q = l >> 4, c = l & 15;
    #pragma unroll
    for (int mt = 0; mt < 2; mt++)
      #pragma unroll
      for (int r = 0; r < 4; r++) {
        int row = m0 + w * 32 + mt * 16 + q * 4 + r;
        int win = row >> 7, tok = row & 127;
        int wd = win >> 8, wh = (win >> 4) & 15, ww = win & 15;
        int td = tok >> 6, th = (tok >> 3) & 7, tw = tok & 7;
        int d = wd * 2 + td + 1; if (d >= 6) d -= 6;
        int h = (wh * 8 + th + 4) & 127;
        int wcol = (ww * 8 + tw + 4) & 127;
        size_t base = ((size_t)((d * 128 + h) * 128 + wcol)) * 180;
        #pragma unroll
        for (int nt = 0; nt < 4; nt++) {
            int col = n0 + nt * 16 + c;
            if (col < 180)
                res[base + col] = xin[base + col] + a1[mt][nt][r] + bias[col];
        }
      }
}

// fc1: K=180, N=360 dual; gelu(x1)*x2 -> hid bf16 [98304][360]
__global__ __launch_bounds__(256) void k_fc1(const bf16* __restrict__ A,
                                             const float* __restrict__ B1,
                                             const float* __restrict__ bb1,
                                             const float* __restrict__ B2,
                                             const float* __restrict__ bb2,
                                             bf16* __restrict__ hid)
{
    f32x4 a1[2][4] = {}, a2[2][4] = {};
    mm_core<180, 360, 192, true>(A, B1, B2, a1, a2);
    int m0 = blockIdx.x * 128, n0 = blockIdx.y * 64;
    int w = threadIdx.x >> 6, l = threadIdx.x & 63, q = l >> 4, c = l & 15;
    #pragma unroll
    for (int mt = 0; mt < 2; mt++)
      #pragma unroll
      for (int nt = 0; nt < 4; nt++)
        #pragma unroll
        for (int r = 0; r < 4; r++) {
            int row = m0 + w * 32 + mt * 16 + q * 4 + r;
            int col = n0 + nt * 16 + c;
            if (col < 360) {
                float gate = a1[mt][nt][r] + bb1[col];
                float gl = 0.5f * gate * (1.f + erff(gate * 0.70710678118654752f));
                hid[(size_t)row * 360 + col] = f2b(gl * (a2[mt][nt][r] + bb2[col]));
            }
        }
}

// fc2: K=360, N=180; out += hid@w2 + b (in-place fp32)
__global__ __launch_bounds__(256) void k_fc2(const bf16* __restrict__ A,
                                             const float* __restrict__ Bw,
                                             const float* __restrict__ bias,
                                             float* __restrict__ out)
{
    f32x4 a1[2][4] = {}, a2[2][4] = {};
    mm_core<360, 180, 360, false>(A, Bw, nullptr, a1, a2);
    int m0 = blockIdx.x * 128, n0 = blockIdx.y * 64;
    int w = threadIdx.x >> 6, l = threadIdx.x & 63, q = l >> 4, c = l & 15;
    #pragma unroll
    for (int mt = 0; mt < 2; mt++)
      #pragma unroll
      for (int nt = 0; nt < 4; nt++)
        #pragma unroll
        for (int r = 0; r < 4; r++) {
            int row = m0 + w * 32 + mt * 16 + q * 4 + r;
            int col = n0 + nt * 16 + c;
            if (col < 180) {
                size_t idx = (size_t)row * 180 + col;
                out[idx] = out[idx] + a1[mt][nt][r] + bias[col];
            }
        }
}

// ---------------------------------------------------------------- MFMA attention
// One block (256 thr = 4 waves) per (window, head). Wave w owns output rows w*32..+31.
// S = Q K^T (hd padded to 32), softmax in C/D regs, P via LDS, O = P V.
// MUT: Q rows swapped (t^64), half-block mask from m2; else rpb+mask bias.
template<bool MUT>
__global__ __launch_bounds__(256) void k_attn(const bf16* __restrict__ qkv,
                                              const float* __restrict__ biasr,
                                              const float* __restrict__ mask,
                                              bf16* __restrict__ aout)
{
    __shared__ __align__(16) bf16 Qs[128 * 40];
    __shared__ __align__(16) bf16 Ks[128 * 40];
    __shared__ __align__(16) bf16 Vts[32 * 136];
    __shared__ __align__(16) bf16 Ps[128 * 136];

    int wh = blockIdx.x, win = wh / 6, nh = wh - win * 6;
    const bf16* qg = qkv + (size_t)wh * 4096;
    const bf16* kg = qg + (size_t)SZPE;
    const bf16* vg = qg + 2 * (size_t)SZPE;
    int tid = threadIdx.x, w = tid >> 6, l = tid & 63, q = l >> 4, c = l & 15;

    { // stage Q (swapped for MUT) and K: 16 elements (2 x uint4) per (row, half)
        int row = tid >> 1, half = tid & 1;
        int qsrc = MUT ? (row ^ 64) : row;
        *(uint4*)&Qs[row * 40 + half * 16]     = *(const uint4*)&qg[qsrc * 32 + half * 16];
        *(uint4*)&Qs[row * 40 + half * 16 + 8] = *(const uint4*)&qg[qsrc * 32 + half * 16 + 8];
        *(uint4*)&Ks[row * 40 + half * 16]     = *(const uint4*)&kg[row  * 32 + half * 16];
        *(uint4*)&Ks[row * 40 + half * 16 + 8] = *(const uint4*)&kg[row  * 32 + half * 16 + 8];
    }
    #pragma unroll
    for (int e = 0; e < 16; e++) {           // stage V transposed
        int gi = e * 256 + tid;              // < 4096
        int tok = gi >> 5, hd = gi & 31;
        Vts[hd * 136 + tok] = vg[gi];
    }
    __syncthreads();

    // ---- S = Q K^T : frags [mt][nt], rows w*32+mt*16+q*4+r, cols nt*16+c
    f32x4 S[2][8];
    #pragma unroll
    for (int mt = 0; mt < 2; mt++)
        #pragma unroll
        for (int nt = 0; nt < 8; nt++) S[mt][nt] = (f32x4){0.f, 0.f, 0.f, 0.f};
    {
        short8 a[2];
        #pragma unroll
        for (int mt = 0; mt < 2; mt++)
            a[mt] = *(const short8*)&Qs[(w * 32 + mt * 16 + c) * 40 + q * 8];
        #pragma unroll
        for (int nt = 0; nt < 8; nt++) {
            short8 b = *(const short8*)&Ks[(nt * 16 + c) * 40 + q * 8];
            #pragma unroll
            for (int mt = 0; mt < 2; mt++) S[mt][nt] = mfma16(a[mt], b, S[mt][nt]);
        }
    }

    // ---- bias + rowmax
    float mx[2][4];
    #pragma unroll
    for (int mt = 0; mt < 2; mt++)
      #pragma unroll
      for (int r = 0; r < 4; r++) mx[mt][r] = -3.0e38f;

    #pragma unroll
    for (int mt = 0; mt < 2; mt++)
      #pragma unroll
      for (int nt = 0; nt < 8; nt++)
        #pragma unroll
        for (int r = 0; r < 4; r++) {
            int row = w * 32 + mt * 16 + q * 4 + r;
            int col = nt * 16 + c;
            float s = S[mt][nt][r];
            if (MUT) {
                bool valid = ((row < 64) == (col < 64));
                s = valid ? s + mask[(size_t)win * 16384 + (row & 63) * 128 + (col & 63)]
                          : -30000.f;
            } else {
                s += biasr[(size_t)nh * 16384 + row * 128 + col]
                   + mask[(size_t)win * 16384 + row * 128 + col];
            }
            S[mt][nt][r] = s;
            mx[mt][r] = fmaxf(mx[mt][r], s);
        }
    #pragma unroll
    for (int mt = 0; mt < 2; mt++)
      #pragma unroll
      for (int r = 0; r < 4; r++) {
          float m = mx[mt][r];
          #pragma unroll
          for (int o = 1; o < 16; o <<= 1) m = fmaxf(m, __shfl_xor(m, o, 64));
          mx[mt][r] = m;
      }

    // ---- p = exp(s - mx), row sums, write P to LDS
    float sm[2][4] = {};
    #pragma unroll
    for (int mt = 0; mt < 2; mt++)
      #pragma unroll
      for (int nt = 0; nt < 8; nt++)
        #pragma unroll
        for (int r = 0; r < 4; r++) {
            float p = __expf(S[mt][nt][r] - mx[mt][r]);
            sm[mt][r] += p;
            Ps[(w * 32 + mt * 16 + q * 4 + r) * 136 + nt * 16 + c] = f2b(p);
        }
    #pragma unroll
    for (int mt = 0; mt < 2; mt++)
      #pragma unroll
      for (int r = 0; r < 4; r++) {
          float s = sm[mt][r];
          #pragma unroll
          for (int o = 1; o < 16; o <<= 1) s += __shfl_xor(s, o, 64);
          sm[mt][r] = s;
      }
    __syncthreads();

    // ---- O = P V : frags [mt][nt], k over 128 tokens
    f32x4 O[2][2];
    #pragma unroll
    for (int mt = 0; mt < 2; mt++)
        #pragma unroll
        for (int nt = 0; nt < 2; nt++) O[mt][nt] = (f32x4){0.f, 0.f, 0.f, 0.f};
    #pragma unroll
    for (int ks = 0; ks < 4; ks++) {
        short8 a[2];
        #pragma unroll
        for (int mt = 0; mt < 2; mt++)
            a[mt] = *(const short8*)&Ps[(w * 32 + mt * 16 + c) * 136 + ks * 32 + q * 8];
        #pragma unroll
        for (int nt = 0; nt < 2; nt++) {
            short8 b = *(const short8*)&Vts[(nt * 16 + c) * 136 + ks * 32 + q * 8];
            #pragma unroll
            for (int mt = 0; mt < 2; mt++) O[mt][nt] = mfma16(a[mt], b, O[mt][nt]);
        }
    }

    // ---- store: aout[win][row][ (MUT?0:180) + nh*30 + col ], col < 30
    #pragma unroll
    for (int mt = 0; mt < 2; mt++)
      #pragma unroll
      for (int r = 0; r < 4; r++) {
          int row = w * 32 + mt * 16 + q * 4 + r;
          float inv = 1.f / sm[mt][r];
          #pragma unroll
          for (int nt = 0; nt < 2; nt++) {
              int col = nt * 16 + c;
              if (col < 30)
                  aout[((size_t)win * 128 + row) * 360 + (MUT ? 0 : 180) + nh * 30 + col] =
                      f2b(O[mt][nt][r] * inv);
          }
      }
}

// ---------------------------------------------------------------- launch
extern "C" void kernel_launch(void* const* d_in, const int* in_sizes, int n_in,
                              void* d_out, int out_size, void* d_ws, size_t ws_size,
                              hipStream_t stream)
{
    const float* x     = (const float*)d_in[0];
    const float* mask  = (const float*)d_in[1];
    const float* g1    = (const float*)d_in[2];
    const float* b1    = (const float*)d_in[3];
    const float* g2    = (const float*)d_in[4];
    const float* b2    = (const float*)d_in[5];
    const float* wqs   = (const float*)d_in[6];
    const float* bqs   = (const float*)d_in[7];
    const float* wqm   = (const float*)d_in[8];
    const float* bqm   = (const float*)d_in[9];
    const float* rpb   = (const float*)d_in[10];
    const float* posb  = (const float*)d_in[11];
    const float* wproj = (const float*)d_in[12];
    const float* bproj = (const float*)d_in[13];
    const float* w11   = (const float*)d_in[14];
    const float* bf11  = (const float*)d_in[15];
    const float* w12   = (const float*)d_in[16];
    const float* bf12  = (const float*)d_in[17];
    const float* w2    = (const float*)d_in[18];
    const float* bf2   = (const float*)d_in[19];
    const int*   rpi   = (const int*)d_in[20];
    float* out = (float*)d_out;

    const size_t need = 259915776;
    if (ws_size < need) { fprintf(stderr, "[tmsa] ws too small: %zu < %zu\n", ws_size, need); return; }

    bf16*  xw    = (bf16*)d_ws;                                  // [98304][192]
    bf16*  xwm   = (bf16*)((char*)d_ws + (size_t)37748736);      // [98304][192]
    bf16*  attn  = (bf16*)((char*)d_ws + (size_t)75497472);      // [98304][360]
    bf16*  qkv   = (bf16*)((char*)d_ws + (size_t)146276352);     // [3][4608][128][32]
    float* biasr = (float*)((char*)d_ws + (size_t)259522560);    // [6][128][128]

    k_rpbg<<<dim3(384), 256, 0, stream>>>(rpb, rpi, biasr);
    k_ln<true><<<dim3(24576), 256, 0, stream>>>(x, g1, b1, posb, xw, xwm);
    k_padzero<<<dim3(6912), 256, 0, stream>>>(qkv);
    k_qkv<<<dim3(768, 9), 256, 0, stream>>>(xw, wqs, bqs, qkv);
    k_attn<false><<<dim3(4608), 256, 0, stream>>>(qkv, biasr, mask, attn);
    k_qkv<<<dim3(768, 9), 256, 0, stream>>>(xwm, wqm, bqm, qkv);
    k_attn<true><<<dim3(4608), 256, 0, stream>>>(qkv, biasr, mask, attn);
    k_proj<<<dim3(768, 3), 256, 0, stream>>>(attn, wproj, bproj, x, out);
    k_ln<false><<<dim3(24576), 256, 0, stream>>>(out, g2, b2, nullptr, xw, nullptr);
    k_fc1<<<dim3(768, 6), 256, 0, stream>>>(xw, w11, bf11, w12, bf12, attn);
    k_fc2<<<dim3(768, 3), 256, 0, stream>>>(attn, w2, bf2, out);
}

// Round 7
// 889.210 us; speedup vs baseline: 3.2664x; 1.5276x over previous
//
#include <hip/hip_runtime.h>
#include <hip/hip_bf16.h>
#include <math.h>
#include <cstdio>

// TMSA block, fp32 I/O, bf16 MFMA internals, pre-packed bf16 weights.
// ws layout (bytes):
//   [0,          37748736)   xw    bf16 [98304][192]  (LN1 out; later LN2 out)
//   [37748736,  75497472)    xwm   bf16 [98304][192]  (xw + pos_bias)
//   [75497472,  150994944)   attn  bf16 [98304][384]  (attn out; later MLP hidden)
//   [150994944, 264241152)   qkv   bf16 [3][4608][128][32] (hd pad 30->32, q pre-scaled)
//   [264241152, 264634368)   biasr fp32 [6][128][128]
//   [264634368, 265671168)   packed weights/biases (see offsets in launch)
// res (x + proj) lives in d_out (fp32), updated in-place by fc2.

typedef __hip_bfloat16 bf16;
typedef __attribute__((ext_vector_type(8))) short short8;
typedef __attribute__((ext_vector_type(4))) float f32x4;

#define SCALE_F 0.18257418583505536f   // 30^-0.5
#define SZPE 18874368u                 // elems per qkv tensor: 4608*128*32

__device__ __forceinline__ bf16  f2b(float v){ return __float2bfloat16(v); }
__device__ __forceinline__ f32x4 mfma16(short8 a, short8 b, f32x4 c){
    return __builtin_amdgcn_mfma_f32_16x16x32_bf16(a, b, c, 0, 0, 0);
}

// ---------------------------------------------------------------- weight packing
// qkv: Bt[576][192] bf16, col n = three*192 + nh*32 + hdp (pad hdp>=30 zero),
// SCALE folded into q (three==0). bb[576] fp32 bias likewise.
__global__ __launch_bounds__(256) void k_pack_qkv(const float* __restrict__ w,
                                                  const float* __restrict__ bias,
                                                  bf16* __restrict__ Bt,
                                                  float* __restrict__ bb)
{
    int idx = blockIdx.x * 256 + threadIdx.x;      // < 110592
    int n = idx / 192, k = idx - n * 192;
    int three = n / 192 == 0 ? (n >> 6) / 3 : 0;   // avoid confusion; compute directly below
    three = n / 192;
    int rem = n - three * 192, nh = rem >> 5, hdp = rem & 31;
    int srcc = three * 180 + nh * 30 + hdp;
    float v = 0.f;
    if (hdp < 30 && k < 180) v = w[(size_t)k * 540 + srcc];
    if (three == 0) v *= SCALE_F;
    Bt[(size_t)n * 192 + k] = f2b(v);
    if (k == 0) bb[n] = (hdp < 30) ? ((three == 0 ? SCALE_F : 1.f) * bias[srcc]) : 0.f;
}

// generic: Bt[n][k] (NP x KP) = w[k][n] (K x NW), zero-padded.
__global__ __launch_bounds__(256) void k_pack(const float* __restrict__ w,
                                              int NW, int K, int KP,
                                              bf16* __restrict__ Bt)
{
    int idx = blockIdx.x * 256 + threadIdx.x;
    int n = idx / KP, k = idx - n * KP;
    float v = (n < NW && k < K) ? w[(size_t)k * NW + n] : 0.f;
    Bt[idx] = f2b(v);
}

// ---------------------------------------------------------------- rpb gather
__global__ __launch_bounds__(256) void k_rpbg(const float* __restrict__ rpb,
                                              const int* __restrict__ rpi,
                                              float* __restrict__ biasr)
{
    int n = blockIdx.x * 256 + threadIdx.x;       // < 98304
    int nh = n >> 14, rc = n & 16383;
    biasr[n] = rpb[rpi[rc] * 6 + nh];
}

// zero attn pad cols 360..383 (stride-384 buffer)
__global__ __launch_bounds__(256) void k_zpad(bf16* __restrict__ attn)
{
    int gi = blockIdx.x * 256 + threadIdx.x;      // < 294912
    int row = gi / 3, part = gi - row * 3;
    *(uint4*)&attn[(size_t)row * 384 + 360 + part * 8] = make_uint4(0u,0u,0u,0u);
}

// ---------------------------------------------------------------- LayerNorm
template<bool ROLL_PB>
__global__ __launch_bounds__(256) void k_ln(const float* __restrict__ x,
                                            const float* __restrict__ g,
                                            const float* __restrict__ b,
                                            const float* __restrict__ pb,
                                            bf16* __restrict__ xw,
                                            bf16* __restrict__ xwm)
{
    int row  = blockIdx.x * 4 + (threadIdx.x >> 6);
    int lane = threadIdx.x & 63;
    const float* src;
    if (ROLL_PB) {
        int win = row >> 7, tok = row & 127;
        int wd = win >> 8, wh = (win >> 4) & 15, ww = win & 15;
        int td = tok >> 6, th = (tok >> 3) & 7, tw = tok & 7;
        int d = wd * 2 + td + 1; if (d >= 6) d -= 6;
        int h = (wh * 8 + th + 4) & 127;
        int w = (ww * 8 + tw + 4) & 127;
        src = x + ((size_t)((d * 128 + h) * 128 + w)) * 180;
    } else {
        src = x + (size_t)row * 180;
    }
    float v0 = src[lane];
    float v1 = src[lane + 64];
    float v2 = (lane < 52) ? src[lane + 128] : 0.f;
    float s  = v0 + v1 + v2;
    float ss = v0*v0 + v1*v1 + v2*v2;
    #pragma unroll
    for (int o = 32; o > 0; o >>= 1) { s += __shfl_xor(s, o, 64); ss += __shfl_xor(ss, o, 64); }
    float mean = s * (1.f/180.f);
    float var  = ss * (1.f/180.f) - mean*mean;
    float rstd = rsqrtf(var + 1e-5f);

    bf16* dst = xw + (size_t)row * 192;
    float y0 = (v0-mean)*rstd*g[lane]     + b[lane];
    float y1 = (v1-mean)*rstd*g[lane+64]  + b[lane+64];
    float y2 = (lane < 52) ? ((v2-mean)*rstd*g[lane+128] + b[lane+128]) : 0.f;
    dst[lane]      = f2b(y0);
    dst[lane+64]   = f2b(y1);
    if (lane < 52) dst[lane+128] = f2b(y2);
    if (lane < 12) dst[180+lane] = f2b(0.f);
    if (ROLL_PB) {
        const float* pbr = pb + (size_t)(row & 63) * 180;
        bf16* dm = xwm + (size_t)row * 192;
        dm[lane]      = f2b(y0 + pbr[lane]);
        dm[lane+64]   = f2b(y1 + pbr[lane+64]);
        if (lane < 52) dm[lane+128] = f2b(y2 + pbr[lane+128]);
        if (lane < 12) dm[180+lane] = f2b(0.f);
    }
}

// ---------------------------------------------------------------- MFMA GEMM core v2
// C[128 x 64] tile of A[M x KP](bf16) @ Bt[N][KP](bf16, pre-transposed).
// All dims padded -> no bounds checks. 4 waves, wave w owns rows w*32..+31.
template<int KP, bool DUAL>
__device__ __forceinline__ void mm2(const bf16* __restrict__ A,
                                    const bf16* __restrict__ Bt1,
                                    const bf16* __restrict__ Bt2,
                                    bf16* As, bf16* Bs1, bf16* Bs2,
                                    int m0, int n0,
                                    f32x4 (&acc1)[2][4], f32x4 (&acc2)[2][4])
{
    const int tid = threadIdx.x;
    const int w = tid >> 6, l = tid & 63, q = l >> 4, c = l & 15;
    #pragma unroll
    for (int ks = 0; ks < KP / 64; ks++) {
        #pragma unroll
        for (int g = 0; g < 4; g++) {
            int gi = g * 256 + tid;             // < 1024
            int m = gi >> 3, kk = (gi & 7) * 8;
            *(uint4*)&As[m * 72 + kk] = *(const uint4*)&A[(size_t)(m0 + m) * KP + ks * 64 + kk];
        }
        #pragma unroll
        for (int g = 0; g < 2; g++) {
            int gi = g * 256 + tid;             // < 512
            int n = gi >> 3, kk = (gi & 7) * 8;
            *(uint4*)&Bs1[n * 72 + kk] = *(const uint4*)&Bt1[(size_t)(n0 + n) * KP + ks * 64 + kk];
            if (DUAL)
                *(uint4*)&Bs2[n * 72 + kk] = *(const uint4*)&Bt2[(size_t)(n0 + n) * KP + ks * 64 + kk];
        }
        __syncthreads();
        #pragma unroll
        for (int k32 = 0; k32 < 2; k32++) {
            short8 a[2];
            #pragma unroll
            for (int mt = 0; mt < 2; mt++)
                a[mt] = *(const short8*)&As[(w * 32 + mt * 16 + c) * 72 + k32 * 32 + q * 8];
            #pragma unroll
            for (int nt = 0; nt < 4; nt++) {
                short8 b1 = *(const short8*)&Bs1[(nt * 16 + c) * 72 + k32 * 32 + q * 8];
                #pragma unroll
                for (int mt = 0; mt < 2; mt++) acc1[mt][nt] = mfma16(a[mt], b1, acc1[mt][nt]);
                if (DUAL) {
                    short8 b2 = *(const short8*)&Bs2[(nt * 16 + c) * 72 + k32 * 32 + q * 8];
                    #pragma unroll
                    for (int mt = 0; mt < 2; mt++) acc2[mt][nt] = mfma16(a[mt], b2, acc2[mt][nt]);
                }
            }
        }
        __syncthreads();
    }
}

// qkv GEMM: KP=192, N=576 packed; vectorized scatter to qkv via LDS roundtrip.
__global__ __launch_bounds__(256) void k_qkv(const bf16* __restrict__ A,
                                             const bf16* __restrict__ Bt,
                                             const float* __restrict__ bb,
                                             bf16* __restrict__ outq)
{
    __shared__ __align__(16) bf16 As[128 * 72];
    __shared__ __align__(16) bf16 Bs[64 * 72];
    int bid = blockIdx.x;                         // 6912 = 768 * 9, n-fastest
    int n0 = (bid % 9) * 64, m0 = (bid / 9) * 128;
    f32x4 a1[2][4] = {}, a2[2][4];
    mm2<192, false>(A, Bt, nullptr, As, Bs, nullptr, m0, n0, a1, a2);

    int tid = threadIdx.x, w = tid >> 6, l = tid & 63, q = l >> 4, c = l & 15;
    bf16* Cs = As;
    #pragma unroll
    for (int mt = 0; mt < 2; mt++)
      #pragma unroll
      for (int nt = 0; nt < 4; nt++)
        #pragma unroll
        for (int r = 0; r < 4; r++) {
            int row = w * 32 + mt * 16 + q * 4 + r;
            int col = n0 + nt * 16 + c;
            Cs[row * 72 + nt * 16 + c] = f2b(a1[mt][nt][r] + bb[col]);
        }
    __syncthreads();
    int win = m0 >> 7;
    #pragma unroll
    for (int e = 0; e < 4; e++) {
        int gi = e * 256 + tid;                   // < 1024
        int row = gi >> 3, c8 = (gi & 7) * 8;
        int col = n0 + c8;
        int three = col / 192, rem = col - three * 192;
        int nh = rem >> 5, hdp = rem & 31;
        bf16* dst = outq + (size_t)three * SZPE + ((size_t)(win * 6 + nh) * 128 + row) * 32 + hdp;
        *(uint4*)dst = *(const uint4*)&Cs[row * 72 + c8];
    }
}

// proj GEMM: KP=384 (attn stride), N pad 192; window-reverse + roll + residual -> d_out.
__global__ __launch_bounds__(256) void k_proj(const bf16* __restrict__ A,
                                              const bf16* __restrict__ Bt,
                                              const float* __restrict__ bias,
                                              const float* __restrict__ xin,
                                              float* __restrict__ res)
{
    __shared__ __align__(16) bf16 As[128 * 72];
    __shared__ __align__(16) bf16 Bs[64 * 72];
    int bid = blockIdx.x;                         // 2304 = 768 * 3
    int n0 = (bid % 3) * 64, m0 = (bid / 3) * 128;
    f32x4 a1[2][4] = {}, a2[2][4];
    mm2<384, false>(A, Bt, nullptr, As, Bs, nullptr, m0, n0, a1, a2);

    int w = threadIdx.x >> 6, l = threadIdx.x & 63, q = l >> 4, c = l & 15;
    #pragma unroll
    for (int mt = 0; mt < 2; mt++)
      #pragma unroll
      for (int r = 0; r < 4; r++) {
        int row = m0 + w * 32 + mt * 16 + q * 4 + r;
        int win = row >> 7, tok = row & 127;
        int wd = win >> 8, wh = (win >> 4) & 15, ww = win & 15;
        int td = tok >> 6, th = (tok >> 3) & 7, tw = tok & 7;
        int d = wd * 2 + td + 1; if (d >= 6) d -= 6;
        int h = (wh * 8 + th + 4) & 127;
        int wcol = (ww * 8 + tw + 4) & 127;
        size_t base = ((size_t)((d * 128 + h) * 128 + wcol)) * 180;
        #pragma unroll
        for (int nt = 0; nt < 4; nt++) {
            int col = n0 + nt * 16 + c;
            if (col < 180)
                res[base + col] = xin[base + col] + a1[mt][nt][r] + bias[col];
        }
      }
}

// fc1: KP=192, N pad 384 dual; gelu(x1)*x2 -> hid [98304][384] via LDS roundtrip.
__global__ __launch_bounds__(256) void k_fc1(const bf16* __restrict__ A,
                                             const bf16* __restrict__ Bt1,
                                             const float* __restrict__ bb1,
                                             const bf16* __restrict__ Bt2,
                                             const float* __restrict__ bb2,
                                             bf16* __restrict__ hid)
{
    __shared__ __align__(16) bf16 As[128 * 72];
    __shared__ __align__(16) bf16 Bs1[64 * 72];
    __shared__ __align__(16) bf16 Bs2[64 * 72];
    int bid = blockIdx.x;                         // 4608 = 768 * 6
    int n0 = (bid % 6) * 64, m0 = (bid / 6) * 128;
    f32x4 a1[2][4] = {}, a2[2][4] = {};
    mm2<192, true>(A, Bt1, Bt2, As, Bs1, Bs2, m0, n0, a1, a2);

    int tid = threadIdx.x, w = tid >> 6, l = tid & 63, q = l >> 4, c = l & 15;
    bf16* Cs = As;
    #pragma unroll
    for (int mt = 0; mt < 2; mt++)
      #pragma unroll
      for (int nt = 0; nt < 4; nt++)
        #pragma unroll
        for (int r = 0; r < 4; r++) {
            int row = w * 32 + mt * 16 + q * 4 + r;
            int col = n0 + nt * 16 + c;
            float hv = 0.f;
            if (col < 360) {
                float gate = a1[mt][nt][r] + bb1[col];
                float gl = 0.5f * gate * (1.f + erff(gate * 0.70710678118654752f));
                hv = gl * (a2[mt][nt][r] + bb2[col]);
            }
            Cs[row * 72 + nt * 16 + c] = f2b(hv);
        }
    __syncthreads();
    #pragma unroll
    for (int e = 0; e < 4; e++) {
        int gi = e * 256 + tid;
        int row = gi >> 3, c8 = (gi & 7) * 8;
        *(uint4*)&hid[(size_t)(m0 + row) * 384 + n0 + c8] = *(const uint4*)&Cs[row * 72 + c8];
    }
}

// fc2: KP=384 (hid stride), N pad 192; out += hid@w2 + b (in-place fp32)
__global__ __launch_bounds__(256) void k_fc2(const bf16* __restrict__ A,
                                             const bf16* __restrict__ Bt,
                                             const float* __restrict__ bias,
                                             float* __restrict__ out)
{
    __shared__ __align__(16) bf16 As[128 * 72];
    __shared__ __align__(16) bf16 Bs[64 * 72];
    int bid = blockIdx.x;                         // 2304
    int n0 = (bid % 3) * 64, m0 = (bid / 3) * 128;
    f32x4 a1[2][4] = {}, a2[2][4];
    mm2<384, false>(A, Bt, nullptr, As, Bs, nullptr, m0, n0, a1, a2);

    int w = threadIdx.x >> 6, l = threadIdx.x & 63, q = l >> 4, c = l & 15;
    #pragma unroll
    for (int mt = 0; mt < 2; mt++)
      #pragma unroll
      for (int nt = 0; nt < 4; nt++)
        #pragma unroll
        for (int r = 0; r < 4; r++) {
            int row = m0 + w * 32 + mt * 16 + q * 4 + r;
            int col = n0 + nt * 16 + c;
            if (col < 180) {
                size_t idx = (size_t)row * 180 + col;
                out[idx] = out[idx] + a1[mt][nt][r] + bias[col];
            }
        }
}

// ---------------------------------------------------------------- MFMA attention
template<bool MUT>
__global__ __launch_bounds__(256) void k_attn(const bf16* __restrict__ qkv,
                                              const float* __restrict__ biasr,
                                              const float* __restrict__ mask,
                                              bf16* __restrict__ aout)
{
    __shared__ __align__(16) bf16 Qs[128 * 40];
    __shared__ __align__(16) bf16 Ks[128 * 40];
    __shared__ __align__(16) bf16 Vts[32 * 136];
    __shared__ __align__(16) bf16 Ps[128 * 136];

    int wh = blockIdx.x, win = wh / 6, nh = wh - win * 6;
    const bf16* qg = qkv + (size_t)wh * 4096;
    const bf16* kg = qg + (size_t)SZPE;
    const bf16* vg = qg + 2 * (size_t)SZPE;
    int tid = threadIdx.x, w = tid >> 6, l = tid & 63, q = l >> 4, c = l & 15;

    { // stage Q (swapped for MUT) and K: 16 elements (2 x uint4) per (row, half)
        int row = tid >> 1, half = tid & 1;
        int qsrc = MUT ? (row ^ 64) : row;
        *(uint4*)&Qs[row * 40 + half * 16]     = *(const uint4*)&qg[qsrc * 32 + half * 16];
        *(uint4*)&Qs[row * 40 + half * 16 + 8] = *(const uint4*)&qg[qsrc * 32 + half * 16 + 8];
        *(uint4*)&Ks[row * 40 + half * 16]     = *(const uint4*)&kg[row  * 32 + half * 16];
        *(uint4*)&Ks[row * 40 + half * 16 + 8] = *(const uint4*)&kg[row  * 32 + half * 16 + 8];
    }
    #pragma unroll
    for (int e = 0; e < 16; e++) {           // stage V transposed
        int gi = e * 256 + tid;              // < 4096
        int tok = gi >> 5, hd = gi & 31;
        Vts[hd * 136 + tok] = vg[gi];
    }
    __syncthreads();

    f32x4 S[2][8];
    #pragma unroll
    for (int mt = 0; mt < 2; mt++)
        #pragma unroll
        for (int nt = 0; nt < 8; nt++) S[mt][nt] = (f32x4){0.f, 0.f, 0.f, 0.f};
    {
        short8 a[2];
        #pragma unroll
        for (int mt = 0; mt < 2; mt++)
            a[mt] = *(const short8*)&Qs[(w * 32 + mt * 16 + c) * 40 + q * 8];
        #pragma unroll
        for (int nt = 0; nt < 8; nt++) {
            short8 b = *(const short8*)&Ks[(nt * 16 + c) * 40 + q * 8];
            #pragma unroll
            for (int mt = 0; mt < 2; mt++) S[mt][nt] = mfma16(a[mt], b, S[mt][nt]);
        }
    }

    float mx[2][4];
    #pragma unroll
    for (int mt = 0; mt < 2; mt++)
      #pragma unroll
      for (int r = 0; r < 4; r++) mx[mt][r] = -3.0e38f;

    #pragma unroll
    for (int mt = 0; mt < 2; mt++)
      #pragma unroll
      for (int nt = 0; nt < 8; nt++)
        #pragma unroll
        for (int r = 0; r < 4; r++) {
            int row = w * 32 + mt * 16 + q * 4 + r;
            int col = nt * 16 + c;
            float s = S[mt][nt][r];
            if (MUT) {
                bool valid = ((row < 64) == (col < 64));
                s = valid ? s + mask[(size_t)win * 16384 + (row & 63) * 128 + (col & 63)]
                          : -30000.f;
            } else {
                s += biasr[(size_t)nh * 16384 + row * 128 + col]
                   + mask[(size_t)win * 16384 + row * 128 + col];
            }
            S[mt][nt][r] = s;
            mx[mt][r] = fmaxf(mx[mt][r], s);
        }
    #pragma unroll
    for (int mt = 0; mt < 2; mt++)
      #pragma unroll
      for (int r = 0; r < 4; r++) {
          float m = mx[mt][r];
          #pragma unroll
          for (int o = 1; o < 16; o <<= 1) m = fmaxf(m, __shfl_xor(m, o, 64));
          mx[mt][r] = m;
      }

    float sm[2][4] = {};
    #pragma unroll
    for (int mt = 0; mt < 2; mt++)
      #pragma unroll
      for (int nt = 0; nt < 8; nt++)
        #pragma unroll
        for (int r = 0; r < 4; r++) {
            float p = __expf(S[mt][nt][r] - mx[mt][r]);
            sm[mt][r] += p;
            Ps[(w * 32 + mt * 16 + q * 4 + r) * 136 + nt * 16 + c] = f2b(p);
        }
    #pragma unroll
    for (int mt = 0; mt < 2; mt++)
      #pragma unroll
      for (int r = 0; r < 4; r++) {
          float s = sm[mt][r];
          #pragma unroll
          for (int o = 1; o < 16; o <<= 1) s += __shfl_xor(s, o, 64);
          sm[mt][r] = s;
      }
    __syncthreads();

    f32x4 O[2][2];
    #pragma unroll
    for (int mt = 0; mt < 2; mt++)
        #pragma unroll
        for (int nt = 0; nt < 2; nt++) O[mt][nt] = (f32x4){0.f, 0.f, 0.f, 0.f};
    #pragma unroll
    for (int ks = 0; ks < 4; ks++) {
        short8 a[2];
        #pragma unroll
        for (int mt = 0; mt < 2; mt++)
            a[mt] = *(const short8*)&Ps[(w * 32 + mt * 16 + c) * 136 + ks * 32 + q * 8];
        #pragma unroll
        for (int nt = 0; nt < 2; nt++) {
            short8 b = *(const short8*)&Vts[(nt * 16 + c) * 136 + ks * 32 + q * 8];
            #pragma unroll
            for (int mt = 0; mt < 2; mt++) O[mt][nt] = mfma16(a[mt], b, O[mt][nt]);
        }
    }

    #pragma unroll
    for (int mt = 0; mt < 2; mt++)
      #pragma unroll
      for (int r = 0; r < 4; r++) {
          int row = w * 32 + mt * 16 + q * 4 + r;
          float inv = 1.f / sm[mt][r];
          #pragma unroll
          for (int nt = 0; nt < 2; nt++) {
              int col = nt * 16 + c;
              if (col < 30)
                  aout[((size_t)win * 128 + row) * 384 + (MUT ? 0 : 180) + nh * 30 + col] =
                      f2b(O[mt][nt][r] * inv);
          }
      }
}

// ---------------------------------------------------------------- launch
extern "C" void kernel_launch(void* const* d_in, const int* in_sizes, int n_in,
                              void* d_out, int out_size, void* d_ws, size_t ws_size,
                              hipStream_t stream)
{
    const float* x     = (const float*)d_in[0];
    const float* mask  = (const float*)d_in[1];
    const float* g1    = (const float*)d_in[2];
    const float* b1    = (const float*)d_in[3];
    const float* g2    = (const float*)d_in[4];
    const float* b2    = (const float*)d_in[5];
    const float* wqs   = (const float*)d_in[6];
    const float* bqs   = (const float*)d_in[7];
    const float* wqm   = (const float*)d_in[8];
    const float* bqm   = (const float*)d_in[9];
    const float* rpb   = (const float*)d_in[10];
    const float* posb  = (const float*)d_in[11];
    const float* wproj = (const float*)d_in[12];
    const float* bproj = (const float*)d_in[13];
    const float* w11   = (const float*)d_in[14];
    const float* bf11  = (const float*)d_in[15];
    const float* w12   = (const float*)d_in[16];
    const float* bf12  = (const float*)d_in[17];
    const float* w2    = (const float*)d_in[18];
    const float* bf2   = (const float*)d_in[19];
    const int*   rpi   = (const int*)d_in[20];
    float* out = (float*)d_out;

    const size_t need = 265671168;
    if (ws_size < need) { fprintf(stderr, "[tmsa] ws too small: %zu < %zu\n", ws_size, need); return; }

    char* W = (char*)d_ws;
    bf16*  xw     = (bf16*)W;                              // [98304][192]
    bf16*  xwm    = (bf16*)(W + 37748736);                 // [98304][192]
    bf16*  attn   = (bf16*)(W + 75497472);                 // [98304][384]
    bf16*  qkv    = (bf16*)(W + 150994944);                // [3][4608][128][32]
    float* biasr  = (float*)(W + 264241152);               // [6][128][128]
    bf16*  Btqs   = (bf16*)(W + 264634368);                // [576][192]
    bf16*  Btqm   = (bf16*)(W + 264855552);                // [576][192]
    float* bbqs   = (float*)(W + 265076736);               // [576]
    float* bbqm   = (float*)(W + 265079040);               // [576]
    bf16*  Btproj = (bf16*)(W + 265081344);                // [192][384]
    bf16*  Btf11  = (bf16*)(W + 265228800);                // [384][192]
    bf16*  Btf12  = (bf16*)(W + 265376256);                // [384][192]
    bf16*  Btf2   = (bf16*)(W + 265523712);                // [192][384]

    k_rpbg<<<dim3(384), 256, 0, stream>>>(rpb, rpi, biasr);
    k_pack_qkv<<<dim3(432), 256, 0, stream>>>(wqs, bqs, Btqs, bbqs);
    k_pack_qkv<<<dim3(432), 256, 0, stream>>>(wqm, bqm, Btqm, bbqm);
    k_pack<<<dim3(288), 256, 0, stream>>>(wproj, 180, 360, 384, Btproj);
    k_pack<<<dim3(288), 256, 0, stream>>>(w11,   360, 180, 192, Btf11);
    k_pack<<<dim3(288), 256, 0, stream>>>(w12,   360, 180, 192, Btf12);
    k_pack<<<dim3(288), 256, 0, stream>>>(w2,    180, 360, 384, Btf2);

    k_ln<true><<<dim3(24576), 256, 0, stream>>>(x, g1, b1, posb, xw, xwm);
    k_zpad<<<dim3(1152), 256, 0, stream>>>(attn);
    k_qkv<<<dim3(6912), 256, 0, stream>>>(xw, Btqs, bbqs, qkv);
    k_attn<false><<<dim3(4608), 256, 0, stream>>>(qkv, biasr, mask, attn);
    k_qkv<<<dim3(6912), 256, 0, stream>>>(xwm, Btqm, bbqm, qkv);
    k_attn<true><<<dim3(4608), 256, 0, stream>>>(qkv, biasr, mask, attn);
    k_proj<<<dim3(2304), 256, 0, stream>>>(attn, Btproj, bproj, x, out);
    k_ln<false><<<dim3(24576), 256, 0, stream>>>(out, g2, b2, nullptr, xw, nullptr);
    k_fc1<<<dim3(4608), 256, 0, stream>>>(xw, Btf11, bf11, Btf12, bf12, attn);
    k_fc2<<<dim3(2304), 256, 0, stream>>>(attn, Btf2, bf2, out);
}